// Round 11
// baseline (137.968 us; speedup 1.0000x reference)
//
#include <hip/hip_runtime.h>

// CloudRasterizerOversample — R11: fixed per-(bucket,chunk) record regions;
// no histogram, no scan, no global cursors, no LDS stage.
// History: R1 global fp32 atomics 171us (23 G/s scattered-atomic wall).
// R6-R10: fused bucket scatter (hist->scan->gcur->stage->grouped write) +
// LDS accum = ~43us ours + ~73us harness floor. R7/R9 tweaks neutral,
// R8/R10 (gcur perturbations) regressed. R11 deletes the whole allocation
// machinery: recs[bucket][chunk][CAPC=24] fixed slots (96MB of the 268MB
// ws; Poisson lambda=4.6 -> P(>=24)~2.5e-11, ~1e-5 expected drops), scatter
// = decode + 1 LDS cursor atomic + direct 8B store + coalesced cnt write.

#define N_PIX_LO 128
#define NBKT 1024            // 64 v-slices x 16 y-bands (8 rows)
#define TPB  1024            // threads per scatter block
#define PPT  4               // points per thread
#define CHUNK (TPB * PPT)    // 4096 points per chunk
#define CAPC 24              // record slots per (bucket, chunk)
#define MAXCH 2048           // max chunks supported (489 actual)
#define TILE_FLOATS 1024     // accum band tile: 8 x 128

typedef unsigned int u32;
typedef unsigned short u16;
typedef unsigned long long u64;
typedef float vf4 __attribute__((ext_vector_type(4)));

constexpr float RCP_PIX = 1.0f / 0.025f;   // correctly-rounded fp32 (== 40.0f)
constexpr float RCP_DV  = 1.0f / 3.125f;   // correctly-rounded fp32

// Reference binning: FOV_HALF_HI=6.3875, PIX_HI=0.025, VEL0_HI=-404.6875,
// DV_HI=3.125 (fp32). Multiply-by-reciprocal differs from IEEE divide by
// <=1 ulp; interior bin flips are weight-continuous, 0-edges sign-exact;
// only the discontinuous 511/255 validity edges get a re-divide guard.
__device__ __forceinline__ bool decode_geom(float vra, float vde, float vve,
    int& cx, int& cy, int& cv, bool& bx, bool& by, bool& bv,
    float& fx, float& fy, float& fv)
{
    float sx = vra + 6.3875f;
    float sy = vde + 6.3875f;
    float sv = vve + 404.6875f;
    float gx = sx * RCP_PIX;
    float gy = sy * RCP_PIX;
    float gv = sv * RCP_DV;
    if (__builtin_expect(fabsf(gx - 511.f) < 1e-3f, 0)) gx = sx / 0.025f;
    if (__builtin_expect(fabsf(gy - 511.f) < 1e-3f, 0)) gy = sy / 0.025f;
    if (__builtin_expect(fabsf(gv - 255.f) < 1e-3f, 0)) gv = sv / 3.125f;
    float fxf = floorf(gx), fyf = floorf(gy), fvf = floorf(gv);
    int ix0 = (int)fxf, iy0 = (int)fyf, iv0 = (int)fvf;
    fx = gx - fxf; fy = gy - fyf; fv = gv - fvf;
    if (ix0 < 0 || ix0 >= 511 || iy0 < 0 || iy0 >= 511 || iv0 < 0 || iv0 >= 255)
        return false;
    cx = ix0 >> 2; cy = iy0 >> 2; cv = iv0 >> 2;
    bx = (ix0 & 3) == 3; by = (iy0 & 3) == 3; bv = (iv0 & 3) == 3;
    return true;
}

__device__ __forceinline__ u64 mk_rec(u32 meta, float w)
{
    return (u64)meta | ((u64)__float_as_uint(w) << 32);
}

// meta: fxq[0:10) fyq[10:20) cx[20:27) cyl[27:30) bx[30] by[31]
__device__ __forceinline__ void emit(u64* __restrict__ recs, u32* hist,
                                     size_t chunk_off, u32 q, u64 rec)
{
    u32 slot = atomicAdd(&hist[q], 1u);
    if (slot < CAPC)
        recs[chunk_off + (size_t)q * ((size_t)CAPC) * 0 /*placeholder*/ ] = rec;
}

__global__ __launch_bounds__(TPB) void k_scatter(
    const float* __restrict__ ra, const float* __restrict__ de,
    const float* __restrict__ vel, const float* __restrict__ flux,
    u16* __restrict__ cnt, u64* __restrict__ recs, int M, int nchunks)
{
    __shared__ u32 hist[NBKT];
    int tid = threadIdx.x;
    int chunk = blockIdx.x;
    hist[tid] = 0;
    __syncthreads();

    int base = chunk * CHUNK;
    float rr[PPT], dd[PPT], vv[PPT], ff[PPT];
    if (base + 4 * tid + 3 < M) {
        int vi = (base >> 2) + tid;
        vf4 r4 = __builtin_nontemporal_load((const vf4*)ra + vi);
        vf4 d4 = __builtin_nontemporal_load((const vf4*)de + vi);
        vf4 v4 = __builtin_nontemporal_load((const vf4*)vel + vi);
        vf4 f4 = __builtin_nontemporal_load((const vf4*)flux + vi);
        rr[0]=r4.x; rr[1]=r4.y; rr[2]=r4.z; rr[3]=r4.w;
        dd[0]=d4.x; dd[1]=d4.y; dd[2]=d4.z; dd[3]=d4.w;
        vv[0]=v4.x; vv[1]=v4.y; vv[2]=v4.z; vv[3]=v4.w;
        ff[0]=f4.x; ff[1]=f4.y; ff[2]=f4.z; ff[3]=f4.w;
    } else {
        #pragma unroll
        for (int k = 0; k < PPT; ++k) {
            int p = base + 4 * tid + k;
            bool ok = p < M;
            rr[k] = ok ? ra[p] : 1e9f;     // 1e9 -> invalid in decode
            dd[k] = ok ? de[p] : 1e9f;
            vv[k] = ok ? vel[p] : 1e9f;
            ff[k] = ok ? flux[p] : 0.f;
        }
    }

    // recs layout: [bucket][chunk][CAPC]; this chunk's region for bucket q
    // starts at (q*nchunks + chunk)*CAPC.
    const size_t cbase = (size_t)chunk * CAPC;
    const size_t bstride = (size_t)nchunks * CAPC;

    #pragma unroll
    for (int k = 0; k < PPT; ++k) {
        int cx, cy, cv; bool bx, by, bv; float fx, fy, fv;
        if (!decode_geom(rr[k], dd[k], vv[k], cx, cy, cv, bx, by, bv, fx, fy, fv))
            continue;
        float f = ff[k] * 0.015625f;        // /64 mean-pool folded in
        int band = cy >> 3, cyl = cy & 7;
        u32 q0 = (u32)((cv << 4) + band);
        bool ys = by && (cyl == 7);
        u32 fxq = (u32)(fx * 1023.f + 0.5f);
        u32 fyq = (u32)(fy * 1023.f + 0.5f);
        u32 mb = fxq | (fyq << 10) | ((u32)cx << 20) | (bx ? (1u << 30) : 0u);
        u32 meta0 = mb | ((u32)cyl << 27) | ((by && !ys) ? (1u << 31) : 0u);
        float wy0 = ys ? (1.f - fy) : 1.f;
        float wv0 = bv ? (1.f - fv) : 1.f;
        float w0 = f * wv0;

        u32 s = atomicAdd(&hist[q0], 1u);
        if (s < CAPC) recs[(size_t)q0 * bstride + cbase + s] = mk_rec(meta0, w0 * wy0);
        if (ys) {
            u32 s2 = atomicAdd(&hist[q0 + 1], 1u);
            if (s2 < CAPC) recs[(size_t)(q0 + 1) * bstride + cbase + s2] = mk_rec(mb, w0 * fy);
        }
        if (bv) {
            float w1 = f * fv;
            u32 s3 = atomicAdd(&hist[q0 + 16], 1u);
            if (s3 < CAPC) recs[(size_t)(q0 + 16) * bstride + cbase + s3] = mk_rec(meta0, w1 * wy0);
            if (ys) {
                u32 s4 = atomicAdd(&hist[q0 + 17], 1u);
                if (s4 < CAPC) recs[(size_t)(q0 + 17) * bstride + cbase + s4] = mk_rec(mb, w1 * fy);
            }
        }
    }
    __syncthreads();

    u32 c = hist[tid];
    cnt[(size_t)chunk * NBKT + tid] = (u16)(c < CAPC ? c : CAPC);
}

__device__ __forceinline__ void accum_rec(u64 rr, float* tile)
{
    u32 m = (u32)rr;
    float w = __uint_as_float((u32)(rr >> 32));
    float fx = (float)(m & 1023u)         * (1.f / 1023.f);
    float fy = (float)((m >> 10) & 1023u) * (1.f / 1023.f);
    int cx  = (m >> 20) & 127;
    int cyl = (m >> 27) & 7;
    bool bx = (m >> 30) & 1u;
    bool by = (m >> 31) != 0u;
    float wx0 = bx ? (1.f - fx) : 1.f;
    float wy0 = by ? (1.f - fy) : 1.f;
    int idx = cyl * N_PIX_LO + cx;
    atomicAdd(&tile[idx], w * wx0 * wy0);
    if (bx) atomicAdd(&tile[idx + 1], w * fx * wy0);
    if (by) {
        atomicAdd(&tile[idx + N_PIX_LO], w * wx0 * fy);
        if (bx) atomicAdd(&tile[idx + N_PIX_LO + 1], w * fx * fy);
    }
}

// grid = NBKT; block q accumulates its 8x128 band in a 4KB LDS tile.
// Flattened (chunk,slot) iteration: consecutive j -> consecutive addresses;
// loads predicated on slot < cnt[chunk].
__global__ __launch_bounds__(256) void k_accum(
    const u16* __restrict__ cnt, const u64* __restrict__ recs,
    float* __restrict__ out, int nchunks)
{
    __shared__ float tile[TILE_FLOATS];
    __shared__ u16 scnt[MAXCH];
    int q = blockIdx.x, t = threadIdx.x;
    #pragma unroll
    for (int i = t; i < TILE_FLOATS; i += 256) tile[i] = 0.f;
    for (int c = t; c < nchunks; c += 256)
        scnt[c] = cnt[(size_t)c * NBKT + q];
    __syncthreads();

    const u64* bp = recs + (size_t)q * nchunks * CAPC;
    int total = nchunks * CAPC;
    for (int j = t; j < total; j += 256) {
        int c = j / CAPC;
        int s = j - c * CAPC;
        if (s < (int)scnt[c])
            accum_rec(bp[j], tile);
    }
    __syncthreads();

    vf4* o = (vf4*)(out + (size_t)q * TILE_FLOATS);
    const vf4* t4 = (const vf4*)tile;
    #pragma unroll
    for (int i = t; i < TILE_FLOATS / 4; i += 256)
        __builtin_nontemporal_store(t4[i], o + i);
}

// ---- fallback: direct global-atomic splat (R1) ----
__global__ __launch_bounds__(256) void k_fallback(
    const float* __restrict__ ra, const float* __restrict__ de,
    const float* __restrict__ vel, const float* __restrict__ flux,
    float* __restrict__ out, int M)
{
    int i = blockIdx.x * blockDim.x + threadIdx.x;
    if (i >= M) return;
    int cx, cy, cv; bool bx, by, bv; float fx, fy, fv;
    if (!decode_geom(ra[i], de[i], vel[i], cx, cy, cv, bx, by, bv, fx, fy, fv)) return;
    float f = flux[i] * 0.015625f;
    float wx0 = bx ? (1.f - fx) : 1.f, wy0 = by ? (1.f - fy) : 1.f, wv0 = bv ? (1.f - fv) : 1.f;
    int nx = bx ? 2 : 1, ny = by ? 2 : 1, nv = bv ? 2 : 1;
    for (int a = 0; a < nv; ++a) {
        float wva = a ? fv : wv0;
        for (int b = 0; b < ny; ++b) {
            float wab = f * wva * (b ? fy : wy0);
            int basei = (((cv + a) * N_PIX_LO) + (cy + b)) * N_PIX_LO + cx;
            for (int c = 0; c < nx; ++c)
                atomicAdd(&out[basei + c], wab * (c ? fx : wx0));
        }
    }
}

extern "C" void kernel_launch(void* const* d_in, const int* in_sizes, int n_in,
                              void* d_out, int out_size, void* d_ws, size_t ws_size,
                              hipStream_t stream) {
    const float* ra   = (const float*)d_in[0];
    const float* de   = (const float*)d_in[1];
    const float* vel  = (const float*)d_in[2];
    const float* flux = (const float*)d_in[3];
    float* out = (float*)d_out;
    int M = in_sizes[0];

    int nchunks = (M + CHUNK - 1) / CHUNK;

    // ws: cnt (nchunks x 1024 u16, reserve 8MB) | recs [1024][nchunks][24] u64
    const size_t recs_off = 8u << 20;
    const size_t need = recs_off + (size_t)NBKT * nchunks * CAPC * sizeof(u64);

    if (nchunks <= MAXCH && ws_size >= need) {
        u16* cnt  = (u16*)d_ws;
        u64* recs = (u64*)((char*)d_ws + recs_off);
        k_scatter<<<nchunks, TPB, 0, stream>>>(ra, de, vel, flux, cnt, recs,
                                               M, nchunks);
        k_accum<<<NBKT, 256, 0, stream>>>(cnt, recs, out, nchunks);
    } else {
        (void)hipMemsetAsync(out, 0, (size_t)out_size * sizeof(float), stream);
        int grid = (M + 255) / 256;
        k_fallback<<<grid, 256, 0, stream>>>(ra, de, vel, flux, out, M);
    }
}

// Round 12
// 131.217 us; speedup vs baseline: 1.0514x; 1.0514x over previous
//
#include <hip/hip_runtime.h>

// CloudRasterizerOversample — R12: R11's minimal scatter + exact-count
// vector-load accum.
// History: R1 global fp32 atomics 171us (23 G/s scattered-atomic wall).
// R6-R10 staged bucket-scatter ~35us + dense accum ~8us. R11 fixed-slot
// scatter = 23us (machinery deleted, WIN) but naive fixed-sweep accum =
// 42us: 12M predicated scalar 8B loads = ~20us of raw VMEM issue.
// R12 accum: per (bucket,chunk) read exact cnt with <=12 predicated 16B
// v2u64 loads (mean 2.3) -> 10x fewer load instructions, no divide.

#define N_PIX_LO 128
#define NBKT 1024            // 64 v-slices x 16 y-bands (8 rows)
#define TPB  1024            // threads per scatter block
#define PPT  4               // points per thread
#define CHUNK (TPB * PPT)    // 4096 points per chunk
#define CAPC 24              // record slots per (bucket, chunk)
#define MAXCH 2048           // max chunks supported (489 actual)
#define TILE_FLOATS 1024     // accum band tile: 8 x 128

typedef unsigned int u32;
typedef unsigned short u16;
typedef unsigned long long u64;
typedef float vf4 __attribute__((ext_vector_type(4)));
typedef u64 v2u64 __attribute__((ext_vector_type(2)));

constexpr float RCP_PIX = 1.0f / 0.025f;   // correctly-rounded fp32 (== 40.0f)
constexpr float RCP_DV  = 1.0f / 3.125f;   // correctly-rounded fp32

// Reference binning: FOV_HALF_HI=6.3875, PIX_HI=0.025, VEL0_HI=-404.6875,
// DV_HI=3.125 (fp32). Multiply-by-reciprocal differs from IEEE divide by
// <=1 ulp; interior bin flips are weight-continuous, 0-edges sign-exact;
// only the discontinuous 511/255 validity edges get a re-divide guard.
__device__ __forceinline__ bool decode_geom(float vra, float vde, float vve,
    int& cx, int& cy, int& cv, bool& bx, bool& by, bool& bv,
    float& fx, float& fy, float& fv)
{
    float sx = vra + 6.3875f;
    float sy = vde + 6.3875f;
    float sv = vve + 404.6875f;
    float gx = sx * RCP_PIX;
    float gy = sy * RCP_PIX;
    float gv = sv * RCP_DV;
    if (__builtin_expect(fabsf(gx - 511.f) < 1e-3f, 0)) gx = sx / 0.025f;
    if (__builtin_expect(fabsf(gy - 511.f) < 1e-3f, 0)) gy = sy / 0.025f;
    if (__builtin_expect(fabsf(gv - 255.f) < 1e-3f, 0)) gv = sv / 3.125f;
    float fxf = floorf(gx), fyf = floorf(gy), fvf = floorf(gv);
    int ix0 = (int)fxf, iy0 = (int)fyf, iv0 = (int)fvf;
    fx = gx - fxf; fy = gy - fyf; fv = gv - fvf;
    if (ix0 < 0 || ix0 >= 511 || iy0 < 0 || iy0 >= 511 || iv0 < 0 || iv0 >= 255)
        return false;
    cx = ix0 >> 2; cy = iy0 >> 2; cv = iv0 >> 2;
    bx = (ix0 & 3) == 3; by = (iy0 & 3) == 3; bv = (iv0 & 3) == 3;
    return true;
}

__device__ __forceinline__ u64 mk_rec(u32 meta, float w)
{
    return (u64)meta | ((u64)__float_as_uint(w) << 32);
}

// meta: fxq[0:10) fyq[10:20) cx[20:27) cyl[27:30) bx[30] by[31]
__global__ __launch_bounds__(TPB) void k_scatter(
    const float* __restrict__ ra, const float* __restrict__ de,
    const float* __restrict__ vel, const float* __restrict__ flux,
    u16* __restrict__ cnt, u64* __restrict__ recs, int M, int nchunks)
{
    __shared__ u32 hist[NBKT];
    int tid = threadIdx.x;
    int chunk = blockIdx.x;
    hist[tid] = 0;
    __syncthreads();

    int base = chunk * CHUNK;
    float rr[PPT], dd[PPT], vv[PPT], ff[PPT];
    if (base + 4 * tid + 3 < M) {
        int vi = (base >> 2) + tid;
        vf4 r4 = __builtin_nontemporal_load((const vf4*)ra + vi);
        vf4 d4 = __builtin_nontemporal_load((const vf4*)de + vi);
        vf4 v4 = __builtin_nontemporal_load((const vf4*)vel + vi);
        vf4 f4 = __builtin_nontemporal_load((const vf4*)flux + vi);
        rr[0]=r4.x; rr[1]=r4.y; rr[2]=r4.z; rr[3]=r4.w;
        dd[0]=d4.x; dd[1]=d4.y; dd[2]=d4.z; dd[3]=d4.w;
        vv[0]=v4.x; vv[1]=v4.y; vv[2]=v4.z; vv[3]=v4.w;
        ff[0]=f4.x; ff[1]=f4.y; ff[2]=f4.z; ff[3]=f4.w;
    } else {
        #pragma unroll
        for (int k = 0; k < PPT; ++k) {
            int p = base + 4 * tid + k;
            bool ok = p < M;
            rr[k] = ok ? ra[p] : 1e9f;     // 1e9 -> invalid in decode
            dd[k] = ok ? de[p] : 1e9f;
            vv[k] = ok ? vel[p] : 1e9f;
            ff[k] = ok ? flux[p] : 0.f;
        }
    }

    // recs layout: [bucket][chunk][CAPC]
    const size_t cbase = (size_t)chunk * CAPC;
    const size_t bstride = (size_t)nchunks * CAPC;

    #pragma unroll
    for (int k = 0; k < PPT; ++k) {
        int cx, cy, cv; bool bx, by, bv; float fx, fy, fv;
        if (!decode_geom(rr[k], dd[k], vv[k], cx, cy, cv, bx, by, bv, fx, fy, fv))
            continue;
        float f = ff[k] * 0.015625f;        // /64 mean-pool folded in
        int band = cy >> 3, cyl = cy & 7;
        u32 q0 = (u32)((cv << 4) + band);
        bool ys = by && (cyl == 7);
        u32 fxq = (u32)(fx * 1023.f + 0.5f);
        u32 fyq = (u32)(fy * 1023.f + 0.5f);
        u32 mb = fxq | (fyq << 10) | ((u32)cx << 20) | (bx ? (1u << 30) : 0u);
        u32 meta0 = mb | ((u32)cyl << 27) | ((by && !ys) ? (1u << 31) : 0u);
        float wy0 = ys ? (1.f - fy) : 1.f;
        float wv0 = bv ? (1.f - fv) : 1.f;
        float w0 = f * wv0;

        u32 s = atomicAdd(&hist[q0], 1u);
        if (s < CAPC) recs[(size_t)q0 * bstride + cbase + s] = mk_rec(meta0, w0 * wy0);
        if (ys) {
            u32 s2 = atomicAdd(&hist[q0 + 1], 1u);
            if (s2 < CAPC) recs[(size_t)(q0 + 1) * bstride + cbase + s2] = mk_rec(mb, w0 * fy);
        }
        if (bv) {
            float w1 = f * fv;
            u32 s3 = atomicAdd(&hist[q0 + 16], 1u);
            if (s3 < CAPC) recs[(size_t)(q0 + 16) * bstride + cbase + s3] = mk_rec(meta0, w1 * wy0);
            if (ys) {
                u32 s4 = atomicAdd(&hist[q0 + 17], 1u);
                if (s4 < CAPC) recs[(size_t)(q0 + 17) * bstride + cbase + s4] = mk_rec(mb, w1 * fy);
            }
        }
    }
    __syncthreads();

    u32 c = hist[tid];
    cnt[(size_t)chunk * NBKT + tid] = (u16)(c < CAPC ? c : CAPC);
}

__device__ __forceinline__ void accum_rec(u64 rr, float* tile)
{
    u32 m = (u32)rr;
    float w = __uint_as_float((u32)(rr >> 32));
    float fx = (float)(m & 1023u)         * (1.f / 1023.f);
    float fy = (float)((m >> 10) & 1023u) * (1.f / 1023.f);
    int cx  = (m >> 20) & 127;
    int cyl = (m >> 27) & 7;
    bool bx = (m >> 30) & 1u;
    bool by = (m >> 31) != 0u;
    float wx0 = bx ? (1.f - fx) : 1.f;
    float wy0 = by ? (1.f - fy) : 1.f;
    int idx = cyl * N_PIX_LO + cx;
    atomicAdd(&tile[idx], w * wx0 * wy0);
    if (bx) atomicAdd(&tile[idx + 1], w * fx * wy0);
    if (by) {
        atomicAdd(&tile[idx + N_PIX_LO], w * wx0 * fy);
        if (bx) atomicAdd(&tile[idx + N_PIX_LO + 1], w * fx * fy);
    }
}

// grid = NBKT; block q accumulates its 8x128 band in a 4KB LDS tile.
// Per chunk: exact-count read, <=CAPC/2 predicated 16B loads (mean 2.3).
__global__ __launch_bounds__(256) void k_accum(
    const u16* __restrict__ cnt, const u64* __restrict__ recs,
    float* __restrict__ out, int nchunks)
{
    __shared__ float tile[TILE_FLOATS];
    __shared__ u16 scnt[MAXCH];
    int q = blockIdx.x, t = threadIdx.x;
    #pragma unroll
    for (int i = t; i < TILE_FLOATS; i += 256) tile[i] = 0.f;
    for (int c = t; c < nchunks; c += 256)
        scnt[c] = cnt[(size_t)c * NBKT + q];
    __syncthreads();

    const v2u64* bp2 = (const v2u64*)(recs + (size_t)q * nchunks * CAPC);
    for (int c = t; c < nchunks; c += 256) {
        int n = scnt[c];
        int base2 = c * (CAPC / 2);
        #pragma unroll
        for (int jj = 0; jj < CAPC / 2; ++jj) {
            if (2 * jj < n) {
                v2u64 r = bp2[base2 + jj];
                accum_rec(r.x, tile);
                if (2 * jj + 1 < n) accum_rec(r.y, tile);
            }
        }
    }
    __syncthreads();

    vf4* o = (vf4*)(out + (size_t)q * TILE_FLOATS);
    const vf4* t4 = (const vf4*)tile;
    #pragma unroll
    for (int i = t; i < TILE_FLOATS / 4; i += 256)
        __builtin_nontemporal_store(t4[i], o + i);
}

// ---- fallback: direct global-atomic splat (R1) ----
__global__ __launch_bounds__(256) void k_fallback(
    const float* __restrict__ ra, const float* __restrict__ de,
    const float* __restrict__ vel, const float* __restrict__ flux,
    float* __restrict__ out, int M)
{
    int i = blockIdx.x * blockDim.x + threadIdx.x;
    if (i >= M) return;
    int cx, cy, cv; bool bx, by, bv; float fx, fy, fv;
    if (!decode_geom(ra[i], de[i], vel[i], cx, cy, cv, bx, by, bv, fx, fy, fv)) return;
    float f = flux[i] * 0.015625f;
    float wx0 = bx ? (1.f - fx) : 1.f, wy0 = by ? (1.f - fy) : 1.f, wv0 = bv ? (1.f - fv) : 1.f;
    int nx = bx ? 2 : 1, ny = by ? 2 : 1, nv = bv ? 2 : 1;
    for (int a = 0; a < nv; ++a) {
        float wva = a ? fv : wv0;
        for (int b = 0; b < ny; ++b) {
            float wab = f * wva * (b ? fy : wy0);
            int basei = (((cv + a) * N_PIX_LO) + (cy + b)) * N_PIX_LO + cx;
            for (int c = 0; c < nx; ++c)
                atomicAdd(&out[basei + c], wab * (c ? fx : wx0));
        }
    }
}

extern "C" void kernel_launch(void* const* d_in, const int* in_sizes, int n_in,
                              void* d_out, int out_size, void* d_ws, size_t ws_size,
                              hipStream_t stream) {
    const float* ra   = (const float*)d_in[0];
    const float* de   = (const float*)d_in[1];
    const float* vel  = (const float*)d_in[2];
    const float* flux = (const float*)d_in[3];
    float* out = (float*)d_out;
    int M = in_sizes[0];

    int nchunks = (M + CHUNK - 1) / CHUNK;

    // ws: cnt (nchunks x 1024 u16, reserve 8MB) | recs [1024][nchunks][24] u64
    const size_t recs_off = 8u << 20;
    const size_t need = recs_off + (size_t)NBKT * nchunks * CAPC * sizeof(u64);

    if (nchunks <= MAXCH && ws_size >= need) {
        u16* cnt  = (u16*)d_ws;
        u64* recs = (u64*)((char*)d_ws + recs_off);
        k_scatter<<<nchunks, TPB, 0, stream>>>(ra, de, vel, flux, cnt, recs,
                                               M, nchunks);
        k_accum<<<NBKT, 256, 0, stream>>>(cnt, recs, out, nchunks);
    } else {
        (void)hipMemsetAsync(out, 0, (size_t)out_size * sizeof(float), stream);
        int grid = (M + 255) / 256;
        k_fallback<<<grid, 256, 0, stream>>>(ra, de, vel, flux, out, M);
    }
}